// Round 5
// baseline (151.361 us; speedup 1.0000x reference)
//
#include <hip/hip_runtime.h>
#include <hip/hip_cooperative_groups.h>
#include <math.h>

namespace cg = cooperative_groups;

#define B_  16
#define C_  256
#define T_  4096
#define DT_ 512
#define NH_ 8
#define HD_ 32

// ---------------------------------------------------------------------------
// k_prep (cooperative, 16 blocks x 512 thr): full text/gate prep chain.
//   A: t1 = gelu(F_text@tp_w1+b1)        [block owns 16 cols, 32-way split-K]
//   G: gate g = sigmoid(f_cond@gp_w+b)   [independent, fills sync slack]
//   B: tv = t1@tp_w2+b2    C: qv = tv@q_w+q_b   D: kq[b,h,c], qkb[b,h]
// grid.sync() between dependent phases.
// ---------------------------------------------------------------------------
__global__ __launch_bounds__(512) void k_prep(
    const float* __restrict__ F_text, const float* __restrict__ U,
    const float* __restrict__ Tt,
    const float* __restrict__ tp_w1, const float* __restrict__ tp_b1,
    const float* __restrict__ tp_w2, const float* __restrict__ tp_b2,
    const float* __restrict__ q_w,  const float* __restrict__ q_b,
    const float* __restrict__ k_w,  const float* __restrict__ k_b,
    const float* __restrict__ fa_w, const float* __restrict__ fa_b,
    const float* __restrict__ gp_w, const float* __restrict__ gp_b,
    float* __restrict__ t1, float* __restrict__ tv, float* __restrict__ qv,
    float* __restrict__ kq, float* __restrict__ qkb, float* __restrict__ gout)
{
    cg::grid_group grid = cg::this_grid();
    __shared__ float xs[8192];
    __shared__ float part[8192];
    __shared__ float pd[2][16][32];
    __shared__ float a0s[16], a1s[16];
    int tid = threadIdx.x;
    int c0  = blockIdx.x * 16;
    int cl  = tid & 15, ks = tid >> 4;      // GEMM mapping: 16 cols x 32 K-slices
    int c   = c0 + cl;

    // ---------- Phase A: t1 (K=512, Kc=16)
    for (int idx = tid; idx < 8192; idx += 512) xs[idx] = F_text[idx];
    __syncthreads();
    {
        float acc[16];
        #pragma unroll
        for (int b = 0; b < 16; ++b) acc[b] = 0.f;
        const float* wp = tp_w1 + (size_t)(ks * 16) * 256 + c;
        #pragma unroll
        for (int i = 0; i < 16; ++i) {
            float w = wp[(size_t)i * 256];
            int xi = ks * 16 + i;
            #pragma unroll
            for (int b = 0; b < 16; ++b) acc[b] += xs[b * 512 + xi] * w;
        }
        #pragma unroll
        for (int b = 0; b < 16; ++b) part[ks * 256 + b * 16 + cl] = acc[b];
    }
    __syncthreads();
    if (tid < 256) {
        int b = tid >> 4, cc = tid & 15;
        float s = 0.f;
        #pragma unroll
        for (int k2 = 0; k2 < 32; ++k2) s += part[k2 * 256 + b * 16 + cc];
        s += tp_b1[c0 + cc];
        s = 0.5f * s * (1.0f + erff(s * 0.70710678118654752f));
        t1[b * 256 + c0 + cc] = s;
    }
    __syncthreads();

    // ---------- Phase G: gate (independent of t1 chain)
    {
        int b = tid >> 5, sl = tid & 31;
        const float* ub = U  + b * 512 + sl * 16;
        const float* tb = Tt + b * 512 + sl * 16;
        const float* fw = fa_w + sl * 16;
        float su = 0.f, st = 0.f;
        #pragma unroll
        for (int j = 0; j < 16; ++j) { su += ub[j] * fw[j]; st += tb[j] * fw[j]; }
        pd[0][b][sl] = su; pd[1][b][sl] = st;
    }
    __syncthreads();
    if (tid < 16) {
        float s0 = fa_b[0], s1 = fa_b[0];
        #pragma unroll
        for (int sl = 0; sl < 32; ++sl) { s0 += pd[0][tid][sl]; s1 += pd[1][tid][sl]; }
        float mm = fmaxf(s0, s1);
        float e0 = expf(s0 - mm), e1 = expf(s1 - mm);
        float inv = 1.0f / (e0 + e1);
        a0s[tid] = e0 * inv; a1s[tid] = e1 * inv;
    }
    __syncthreads();
    for (int idx = tid; idx < 8192; idx += 512) {
        int b = idx >> 9;
        xs[idx] = a0s[b] * U[idx] + a1s[b] * Tt[idx];
    }
    __syncthreads();
    {
        float acc[16];
        #pragma unroll
        for (int b = 0; b < 16; ++b) acc[b] = 0.f;
        const float* wp = gp_w + (size_t)(ks * 16) * 256 + c;
        #pragma unroll
        for (int i = 0; i < 16; ++i) {
            float w = wp[(size_t)i * 256];
            int xi = ks * 16 + i;
            #pragma unroll
            for (int b = 0; b < 16; ++b) acc[b] += xs[b * 512 + xi] * w;
        }
        #pragma unroll
        for (int b = 0; b < 16; ++b) part[ks * 256 + b * 16 + cl] = acc[b];
    }
    __syncthreads();
    if (tid < 256) {
        int b = tid >> 4, cc = tid & 15;
        float s = 0.f;
        #pragma unroll
        for (int k2 = 0; k2 < 32; ++k2) s += part[k2 * 256 + b * 16 + cc];
        s += gp_b[c0 + cc];
        gout[b * 256 + c0 + cc] = 1.0f / (1.0f + expf(-s));
    }
    grid.sync();

    // ---------- Phase B: tv (K=256, Kc=8)
    for (int idx = tid; idx < 4096; idx += 512) xs[idx] = t1[idx];
    __syncthreads();
    {
        float acc[16];
        #pragma unroll
        for (int b = 0; b < 16; ++b) acc[b] = 0.f;
        const float* wp = tp_w2 + (size_t)(ks * 8) * 256 + c;
        #pragma unroll
        for (int i = 0; i < 8; ++i) {
            float w = wp[(size_t)i * 256];
            int xi = ks * 8 + i;
            #pragma unroll
            for (int b = 0; b < 16; ++b) acc[b] += xs[b * 256 + xi] * w;
        }
        #pragma unroll
        for (int b = 0; b < 16; ++b) part[ks * 256 + b * 16 + cl] = acc[b];
    }
    __syncthreads();
    if (tid < 256) {
        int b = tid >> 4, cc = tid & 15;
        float s = 0.f;
        #pragma unroll
        for (int k2 = 0; k2 < 32; ++k2) s += part[k2 * 256 + b * 16 + cc];
        tv[b * 256 + c0 + cc] = s + tp_b2[c0 + cc];
    }
    grid.sync();

    // ---------- Phase C: qv
    for (int idx = tid; idx < 4096; idx += 512) xs[idx] = tv[idx];
    __syncthreads();
    {
        float acc[16];
        #pragma unroll
        for (int b = 0; b < 16; ++b) acc[b] = 0.f;
        const float* wp = q_w + (size_t)(ks * 8) * 256 + c;
        #pragma unroll
        for (int i = 0; i < 8; ++i) {
            float w = wp[(size_t)i * 256];
            int xi = ks * 8 + i;
            #pragma unroll
            for (int b = 0; b < 16; ++b) acc[b] += xs[b * 256 + xi] * w;
        }
        #pragma unroll
        for (int b = 0; b < 16; ++b) part[ks * 256 + b * 16 + cl] = acc[b];
    }
    __syncthreads();
    if (tid < 256) {
        int b = tid >> 4, cc = tid & 15;
        float s = 0.f;
        #pragma unroll
        for (int k2 = 0; k2 < 32; ++k2) s += part[k2 * 256 + b * 16 + cc];
        qv[b * 256 + c0 + cc] = s + q_b[c0 + cc];
    }
    grid.sync();

    // ---------- Phase D: kq + qkb
    for (int idx = tid; idx < 4096; idx += 512) xs[idx] = qv[idx];
    __syncthreads();
    {
        int cl2 = tid >> 5;          // 0..15
        int h   = (tid >> 2) & 7;    // 0..7
        int bq  = tid & 3;           // 0..3 (4 batches each)
        int cD  = c0 + cl2;
        const float* kwp = k_w + (size_t)cD * 256 + h * 32;
        float acc[4] = {0, 0, 0, 0};
        #pragma unroll
        for (int dd = 0; dd < 32; ++dd) {
            int d = (dd + h * 4) & 31;
            float w = kwp[d];
            #pragma unroll
            for (int bi = 0; bi < 4; ++bi)
                acc[bi] += xs[(bq * 4 + bi) * 256 + h * 32 + d] * w;
        }
        #pragma unroll
        for (int bi = 0; bi < 4; ++bi)
            kq[((size_t)((bq * 4 + bi) * 8 + h)) * 256 + cD] = acc[bi];
    }
    if (blockIdx.x == 0 && tid < 128) {
        int b = tid >> 3, hh = tid & 7;
        float s = 0.f;
        #pragma unroll
        for (int d = 0; d < 32; ++d) s += xs[b * 256 + hh * 32 + d] * k_b[hh * 32 + d];
        qkb[b * 8 + hh] = s;
    }
}

// ---------------------------------------------------------------------------
// K2: score partials, float4 along t, c split 4-way.
// ---------------------------------------------------------------------------
__global__ __launch_bounds__(256) void k2_scores(const float* __restrict__ F_vis,
                                                 const float* __restrict__ kq,
                                                 float* __restrict__ sp)
{
    int bx = blockIdx.x;
    int b  = blockIdx.y;
    int cq = bx >> 2;
    int tc = bx & 3;
    int tid = threadIdx.x;
    int t  = tc * 1024 + tid * 4;

    __shared__ float kqs[64][8];
    for (int idx = tid; idx < 512; idx += 256) {
        int h = idx & 7, cl = idx >> 3;
        kqs[cl][h] = kq[((size_t)(b * NH_ + h)) * C_ + cq * 64 + cl];
    }
    __syncthreads();

    const float* fv = F_vis + ((size_t)b * C_ + cq * 64) * T_ + t;

    float4 acc[8];
    #pragma unroll
    for (int h = 0; h < 8; ++h) acc[h] = make_float4(0.f, 0.f, 0.f, 0.f);

    for (int cl = 0; cl < 64; ++cl) {
        float4 v = *reinterpret_cast<const float4*>(&fv[(size_t)cl * T_]);
        #pragma unroll
        for (int h = 0; h < 8; ++h) {
            float w = kqs[cl][h];
            acc[h].x += v.x * w; acc[h].y += v.y * w;
            acc[h].z += v.z * w; acc[h].w += v.w * w;
        }
    }
    #pragma unroll
    for (int h = 0; h < 8; ++h)
        *reinterpret_cast<float4*>(&sp[(((size_t)cq * B_ + b) * NH_ + h) * T_ + t]) = acc[h];
}

// ---------------------------------------------------------------------------
// K3: softmax over T per (b,h) from 4 partials; writes attn output
// ---------------------------------------------------------------------------
__global__ __launch_bounds__(256) void k3_softmax(const float* __restrict__ sp,
                                                  const float* __restrict__ qkb,
                                                  float* __restrict__ attn)
{
    int h = blockIdx.x, b = blockIdx.y, tid = threadIdx.x;
    const float scale = 0.176776695296636893f;  // 32^-0.5
    float bias = qkb[b * NH_ + h];
    const float* p0 = sp + (((size_t)0 * B_ + b) * NH_ + h) * T_;
    const float* p1 = sp + (((size_t)1 * B_ + b) * NH_ + h) * T_;
    const float* p2 = sp + (((size_t)2 * B_ + b) * NH_ + h) * T_;
    const float* p3 = sp + (((size_t)3 * B_ + b) * NH_ + h) * T_;

    float4 sv[4];
    float m = -1e30f;
    #pragma unroll
    for (int k = 0; k < 4; ++k) {
        int t = k * 1024 + tid * 4;
        float4 a = *reinterpret_cast<const float4*>(&p0[t]);
        float4 c = *reinterpret_cast<const float4*>(&p1[t]);
        float4 d = *reinterpret_cast<const float4*>(&p2[t]);
        float4 e = *reinterpret_cast<const float4*>(&p3[t]);
        float4 v;
        v.x = (a.x + c.x + d.x + e.x + bias) * scale;
        v.y = (a.y + c.y + d.y + e.y + bias) * scale;
        v.z = (a.z + c.z + d.z + e.z + bias) * scale;
        v.w = (a.w + c.w + d.w + e.w + bias) * scale;
        sv[k] = v;
        m = fmaxf(m, fmaxf(fmaxf(v.x, v.y), fmaxf(v.z, v.w)));
    }
    __shared__ float red[8];
    #pragma unroll
    for (int o = 32; o; o >>= 1) m = fmaxf(m, __shfl_xor(m, o));
    int wid = tid >> 6, lane = tid & 63;
    if (lane == 0) red[wid] = m;
    __syncthreads();
    m = fmaxf(fmaxf(red[0], red[1]), fmaxf(red[2], red[3]));

    float sum = 0.f;
    #pragma unroll
    for (int k = 0; k < 4; ++k) {
        sv[k].x = expf(sv[k].x - m); sv[k].y = expf(sv[k].y - m);
        sv[k].z = expf(sv[k].z - m); sv[k].w = expf(sv[k].w - m);
        sum += sv[k].x + sv[k].y + sv[k].z + sv[k].w;
    }
    #pragma unroll
    for (int o = 32; o; o >>= 1) sum += __shfl_xor(sum, o);
    if (lane == 0) red[4 + wid] = sum;
    __syncthreads();
    sum = red[4] + red[5] + red[6] + red[7];
    float inv = 1.0f / sum;

    float* ap = attn + ((size_t)b * NH_ + h) * T_;
    #pragma unroll
    for (int k = 0; k < 4; ++k) {
        float4 v = sv[k];
        v.x *= inv; v.y *= inv; v.z *= inv; v.w *= inv;
        *reinterpret_cast<float4*>(&ap[k * 1024 + tid * 4]) = v;
    }
}

// ---------------------------------------------------------------------------
// K4: xa partials over half-t ranges (z = 0,1).  wave owns 4 channels.
// xa[z][b][h][c] = sum_{t in half z} attn[b,h,t] * F_vis[b,c,t]
// ---------------------------------------------------------------------------
__global__ __launch_bounds__(256, 2) void k4_xa(const float* __restrict__ F_vis,
                                                const float* __restrict__ attn,
                                                float* __restrict__ xa)
{
    int b = blockIdx.y, z = blockIdx.z;
    int tid = threadIdx.x, wid = tid >> 6, lane = tid & 63;
    int c0 = blockIdx.x * 16 + wid * 4;

    const float* ab = attn + (size_t)b * NH_ * T_;
    const float* fb = F_vis + (size_t)b * C_ * T_;

    float4 acc[4][8];
    #pragma unroll
    for (int j = 0; j < 4; ++j)
        #pragma unroll
        for (int h = 0; h < 8; ++h) acc[j][h] = make_float4(0.f, 0.f, 0.f, 0.f);

    for (int it = 0; it < 8; ++it) {
        int t = z * 2048 + it * 256 + lane * 4;
        float4 av[8];
        #pragma unroll
        for (int h = 0; h < 8; ++h)
            av[h] = *reinterpret_cast<const float4*>(&ab[(size_t)h * T_ + t]);
        #pragma unroll
        for (int j = 0; j < 4; ++j) {
            float4 f = *reinterpret_cast<const float4*>(&fb[(size_t)(c0 + j) * T_ + t]);
            #pragma unroll
            for (int h = 0; h < 8; ++h) {
                acc[j][h].x += f.x * av[h].x; acc[j][h].y += f.y * av[h].y;
                acc[j][h].z += f.z * av[h].z; acc[j][h].w += f.w * av[h].w;
            }
        }
    }
    #pragma unroll
    for (int j = 0; j < 4; ++j)
        #pragma unroll
        for (int h = 0; h < 8; ++h) {
            float v = acc[j][h].x + acc[j][h].y + acc[j][h].z + acc[j][h].w;
            #pragma unroll
            for (int o = 32; o; o >>= 1) v += __shfl_xor(v, o);
            if (lane == 0)
                xa[(((size_t)z * B_ + b) * NH_ + h) * C_ + c0 + j] = v;
        }
}

// ---------------------------------------------------------------------------
// K5: z = ((xa0+xa1) @ v_w + v_b) @ o_w + o_b;  gz = g * z
// ---------------------------------------------------------------------------
__global__ void k5_z(const float* __restrict__ xa,
                     const float* __restrict__ v_w, const float* __restrict__ v_b,
                     const float* __restrict__ o_w, const float* __restrict__ o_b,
                     const float* __restrict__ g,   float* __restrict__ gz)
{
    int b = blockIdx.x, j = threadIdx.x;
    __shared__ float zp[C_];
    int h = j >> 5;
    float s = v_b[j];
    const float* xr0 = xa + (((size_t)0 * B_ + b) * NH_ + h) * C_;
    const float* xr1 = xa + (((size_t)1 * B_ + b) * NH_ + h) * C_;
    #pragma unroll 8
    for (int c = 0; c < C_; c++) s += (xr0[c] + xr1[c]) * v_w[c * C_ + j];
    zp[j] = s;
    __syncthreads();
    float z = o_b[j];
    #pragma unroll 8
    for (int i = 0; i < C_; i++) z += zp[i] * o_w[i * C_ + j];
    gz[b * C_ + j] = g[b * C_ + j] * z;
}

// ---------------------------------------------------------------------------
// K6: fused residual+gate+LayerNorm, register-resident, shfl-reduce.
// Block = [256 c][32 t]; thread owns (t-quad = tid&7, 8 c at stride 32).
// ---------------------------------------------------------------------------
__global__ __launch_bounds__(256) void k6_ln(const float* __restrict__ F_vis,
                                             const float* __restrict__ gz,
                                             const float* __restrict__ ln_g,
                                             const float* __restrict__ ln_b,
                                             float* __restrict__ out)
{
    int b  = blockIdx.y;
    int t0 = blockIdx.x * 32;
    int tid = threadIdx.x;
    int t4 = tid & 7;            // which float4 of the 32-t tile
    int cb = tid >> 3;           // 0..31 base channel

    __shared__ float gzs[256], lgs[256], lbs[256];
    __shared__ float4 redS[4][8], redQ[4][8];
    __shared__ float4 mu4s[8], rs4s[8];

    gzs[tid] = gz[b * C_ + tid];
    lgs[tid] = ln_g[tid];
    lbs[tid] = ln_b[tid];
    __syncthreads();

    const float* fvb = F_vis + (size_t)b * C_ * T_ + t0 + t4 * 4;
    float4 v[8];
    float4 s = make_float4(0.f, 0.f, 0.f, 0.f);
    float4 q = make_float4(0.f, 0.f, 0.f, 0.f);
    #pragma unroll
    for (int k = 0; k < 8; ++k) {
        int c = cb + k * 32;
        float4 x = *reinterpret_cast<const float4*>(&fvb[(size_t)c * T_]);
        float gc = gzs[c];
        x.x += gc; x.y += gc; x.z += gc; x.w += gc;
        v[k] = x;
        s.x += x.x; s.y += x.y; s.z += x.z; s.w += x.w;
        q.x += x.x * x.x; q.y += x.y * x.y; q.z += x.z * x.z; q.w += x.w * x.w;
    }
    // reduce across the 8 within-wave c-groups (lane bits 3..5)
    #pragma unroll
    for (int o = 8; o <= 32; o <<= 1) {
        s.x += __shfl_xor(s.x, o); s.y += __shfl_xor(s.y, o);
        s.z += __shfl_xor(s.z, o); s.w += __shfl_xor(s.w, o);
        q.x += __shfl_xor(q.x, o); q.y += __shfl_xor(q.y, o);
        q.z += __shfl_xor(q.z, o); q.w += __shfl_xor(q.w, o);
    }
    int wid = tid >> 6;
    if ((tid & 63) < 8) { redS[wid][t4] = s; redQ[wid][t4] = q; }
    __syncthreads();
    if (tid < 8) {
        float4 S = redS[0][tid], Q = redQ[0][tid];
        #pragma unroll
        for (int w = 1; w < 4; ++w) {
            float4 a = redS[w][tid], c2 = redQ[w][tid];
            S.x += a.x; S.y += a.y; S.z += a.z; S.w += a.w;
            Q.x += c2.x; Q.y += c2.y; Q.z += c2.z; Q.w += c2.w;
        }
        float4 mu, rs;
        mu.x = S.x * (1.0f / C_); mu.y = S.y * (1.0f / C_);
        mu.z = S.z * (1.0f / C_); mu.w = S.w * (1.0f / C_);
        rs.x = rsqrtf(fmaxf(Q.x * (1.0f / C_) - mu.x * mu.x, 0.f) + 1e-5f);
        rs.y = rsqrtf(fmaxf(Q.y * (1.0f / C_) - mu.y * mu.y, 0.f) + 1e-5f);
        rs.z = rsqrtf(fmaxf(Q.z * (1.0f / C_) - mu.z * mu.z, 0.f) + 1e-5f);
        rs.w = rsqrtf(fmaxf(Q.w * (1.0f / C_) - mu.w * mu.w, 0.f) + 1e-5f);
        mu4s[tid] = mu; rs4s[tid] = rs;
    }
    __syncthreads();
    float4 mu = mu4s[t4], rs = rs4s[t4];
    float* ob = out + (size_t)b * C_ * T_ + t0 + t4 * 4;
    #pragma unroll
    for (int k = 0; k < 8; ++k) {
        int c = cb + k * 32;
        float lg = lgs[c], lb = lbs[c];
        float4 o;
        o.x = (v[k].x - mu.x) * rs.x * lg + lb;
        o.y = (v[k].y - mu.y) * rs.y * lg + lb;
        o.z = (v[k].z - mu.z) * rs.z * lg + lb;
        o.w = (v[k].w - mu.w) * rs.w * lg + lb;
        *reinterpret_cast<float4*>(&ob[(size_t)c * T_]) = o;
    }
}

// ---------------------------------------------------------------------------
extern "C" void kernel_launch(void* const* d_in, const int* in_sizes, int n_in,
                              void* d_out, int out_size, void* d_ws, size_t ws_size,
                              hipStream_t stream)
{
    const float* F_vis     = (const float*)d_in[0];
    const float* F_text    = (const float*)d_in[1];
    const float* F_unified = (const float*)d_in[2];
    const float* F_teacher = (const float*)d_in[3];
    const float* tp_w1 = (const float*)d_in[4];
    const float* tp_b1 = (const float*)d_in[5];
    const float* tp_w2 = (const float*)d_in[6];
    const float* tp_b2 = (const float*)d_in[7];
    const float* q_w   = (const float*)d_in[8];
    const float* q_b   = (const float*)d_in[9];
    const float* k_w   = (const float*)d_in[10];
    const float* k_b   = (const float*)d_in[11];
    const float* v_w   = (const float*)d_in[12];
    const float* v_b   = (const float*)d_in[13];
    const float* o_w   = (const float*)d_in[14];
    const float* o_b   = (const float*)d_in[15];
    const float* fa_w  = (const float*)d_in[16];
    const float* fa_b  = (const float*)d_in[17];
    const float* gp_w  = (const float*)d_in[18];
    const float* gp_b  = (const float*)d_in[19];
    const float* ln_g  = (const float*)d_in[20];
    const float* ln_b  = (const float*)d_in[21];

    float* ws  = (float*)d_ws;
    float* t1  = ws;                    // 4096
    float* tv  = ws + 4096;             // 4096
    float* qv  = ws + 8192;             // 4096
    float* kq  = ws + 12288;            // 32768
    float* qkb = ws + 45056;            // 128
    float* g   = ws + 45184;            // 4096
    float* gz  = ws + 49280;            // 4096
    float* xa  = ws + 53376;            // 2 x 32768 = 65536

    float* out  = (float*)d_out;
    float* attn = out + (size_t)B_ * C_ * T_;    // output #1 region
    float* sp   = out;                           // scratch in y-region (8 MiB)

    void* prep_args[] = {
        (void*)&F_text, (void*)&F_unified, (void*)&F_teacher,
        (void*)&tp_w1, (void*)&tp_b1, (void*)&tp_w2, (void*)&tp_b2,
        (void*)&q_w, (void*)&q_b, (void*)&k_w, (void*)&k_b,
        (void*)&fa_w, (void*)&fa_b, (void*)&gp_w, (void*)&gp_b,
        (void*)&t1, (void*)&tv, (void*)&qv, (void*)&kq, (void*)&qkb, (void*)&g
    };
    hipLaunchCooperativeKernel((void*)k_prep, dim3(16), dim3(512),
                               prep_args, 0, stream);

    k2_scores<<<dim3(16, B_), 256, 0, stream>>>(F_vis, kq, sp);
    k3_softmax<<<dim3(NH_, B_), 256, 0, stream>>>(sp, qkb, attn);
    k4_xa<<<dim3(16, B_, 2), 256, 0, stream>>>(F_vis, attn, xa);
    k5_z<<<B_, 256, 0, stream>>>(xa, v_w, v_b, o_w, o_b, g, gz);
    k6_ln<<<dim3(128, B_), 256, 0, stream>>>(F_vis, gz, ln_g, ln_b, out);
}

// Round 6
// 115.837 us; speedup vs baseline: 1.3067x; 1.3067x over previous
//
#include <hip/hip_runtime.h>
#include <math.h>

#define B_  16
#define C_  256
#define T_  4096
#define DT_ 512
#define NH_ 8
#define HD_ 32

// ---------------------------------------------------------------------------
// k_t1gate (16 blocks x 512 thr): two independent phases.
//   A: t1 = gelu(F_text@tp_w1+b1)   [block owns 16 cols, 32-way split-K]
//   G: g  = sigmoid(f_cond@gp_w+b)  [gate scalars computed redundantly]
// ---------------------------------------------------------------------------
__global__ __launch_bounds__(512) void k_t1gate(
    const float* __restrict__ F_text, const float* __restrict__ U,
    const float* __restrict__ Tt,
    const float* __restrict__ tp_w1, const float* __restrict__ tp_b1,
    const float* __restrict__ fa_w,  const float* __restrict__ fa_b,
    const float* __restrict__ gp_w,  const float* __restrict__ gp_b,
    float* __restrict__ t1, float* __restrict__ gout)
{
    __shared__ float xs[8192];
    __shared__ float part[8192];
    __shared__ float pd[2][16][32];
    __shared__ float a0s[16], a1s[16];
    int tid = threadIdx.x;
    int c0  = blockIdx.x * 16;
    int cl  = tid & 15, ks = tid >> 4;
    int c   = c0 + cl;

    // ---- Phase A: t1 (K=512, Kc=16)
    for (int idx = tid; idx < 8192; idx += 512) xs[idx] = F_text[idx];
    __syncthreads();
    {
        float acc[16];
        #pragma unroll
        for (int b = 0; b < 16; ++b) acc[b] = 0.f;
        const float* wp = tp_w1 + (size_t)(ks * 16) * 256 + c;
        #pragma unroll
        for (int i = 0; i < 16; ++i) {
            float w = wp[(size_t)i * 256];
            int xi = ks * 16 + i;
            #pragma unroll
            for (int b = 0; b < 16; ++b) acc[b] += xs[b * 512 + xi] * w;
        }
        #pragma unroll
        for (int b = 0; b < 16; ++b) part[ks * 256 + b * 16 + cl] = acc[b];
    }
    __syncthreads();
    if (tid < 256) {
        int b = tid >> 4, cc = tid & 15;
        float s = 0.f;
        #pragma unroll
        for (int k2 = 0; k2 < 32; ++k2) s += part[k2 * 256 + b * 16 + cc];
        s += tp_b1[c0 + cc];
        s = 0.5f * s * (1.0f + erff(s * 0.70710678118654752f));
        t1[b * 256 + c0 + cc] = s;
    }
    __syncthreads();

    // ---- Phase G: gate
    {
        int b = tid >> 5, sl = tid & 31;
        const float* ub = U  + b * 512 + sl * 16;
        const float* tb = Tt + b * 512 + sl * 16;
        const float* fw = fa_w + sl * 16;
        float su = 0.f, st = 0.f;
        #pragma unroll
        for (int j = 0; j < 16; ++j) { su += ub[j] * fw[j]; st += tb[j] * fw[j]; }
        pd[0][b][sl] = su; pd[1][b][sl] = st;
    }
    __syncthreads();
    if (tid < 16) {
        float s0 = fa_b[0], s1 = fa_b[0];
        #pragma unroll
        for (int sl = 0; sl < 32; ++sl) { s0 += pd[0][tid][sl]; s1 += pd[1][tid][sl]; }
        float mm = fmaxf(s0, s1);
        float e0 = expf(s0 - mm), e1 = expf(s1 - mm);
        float inv = 1.0f / (e0 + e1);
        a0s[tid] = e0 * inv; a1s[tid] = e1 * inv;
    }
    __syncthreads();
    for (int idx = tid; idx < 8192; idx += 512) {
        int b = idx >> 9;
        xs[idx] = a0s[b] * U[idx] + a1s[b] * Tt[idx];
    }
    __syncthreads();
    {
        float acc[16];
        #pragma unroll
        for (int b = 0; b < 16; ++b) acc[b] = 0.f;
        const float* wp = gp_w + (size_t)(ks * 16) * 256 + c;
        #pragma unroll
        for (int i = 0; i < 16; ++i) {
            float w = wp[(size_t)i * 256];
            int xi = ks * 16 + i;
            #pragma unroll
            for (int b = 0; b < 16; ++b) acc[b] += xs[b * 512 + xi] * w;
        }
        #pragma unroll
        for (int b = 0; b < 16; ++b) part[ks * 256 + b * 16 + cl] = acc[b];
    }
    __syncthreads();
    if (tid < 256) {
        int b = tid >> 4, cc = tid & 15;
        float s = 0.f;
        #pragma unroll
        for (int k2 = 0; k2 < 32; ++k2) s += part[k2 * 256 + b * 16 + cc];
        s += gp_b[c0 + cc];
        gout[b * 256 + c0 + cc] = 1.0f / (1.0f + expf(-s));
    }
}

// ---------------------------------------------------------------------------
// gemm16<K,ACT>: out[16][256] = act(x[16][K] @ W[K][256] + bias)  (tv step)
// ---------------------------------------------------------------------------
template<int K, int ACT>
__global__ __launch_bounds__(512) void gemm16(const float* __restrict__ x,
                                              const float* __restrict__ W,
                                              const float* __restrict__ bias,
                                              float* __restrict__ out)
{
    __shared__ float xs[16 * K];
    __shared__ float part[32 * 256];
    int tid = threadIdx.x;
    int c0  = blockIdx.x * 16;

    for (int idx = tid; idx < 16 * K; idx += 512) xs[idx] = x[idx];
    __syncthreads();

    int cl = tid & 15, ks = tid >> 4;
    const int Kc = K / 32;
    int c = c0 + cl;

    float acc[16];
    #pragma unroll
    for (int b = 0; b < 16; ++b) acc[b] = 0.f;

    const float* wp = W + (size_t)(ks * Kc) * 256 + c;
    #pragma unroll
    for (int i = 0; i < Kc; ++i) {
        float w  = wp[(size_t)i * 256];
        int   xi = ks * Kc + i;
        #pragma unroll
        for (int b = 0; b < 16; ++b) acc[b] += xs[b * K + xi] * w;
    }
    #pragma unroll
    for (int b = 0; b < 16; ++b) part[ks * 256 + b * 16 + cl] = acc[b];
    __syncthreads();

    if (tid < 256) {
        int b = tid >> 4, cc = tid & 15;
        float s = 0.f;
        #pragma unroll
        for (int k2 = 0; k2 < 32; ++k2) s += part[k2 * 256 + b * 16 + cc];
        s += bias[c0 + cc];
        if (ACT == 1) s = 0.5f * s * (1.0f + erff(s * 0.70710678118654752f));
        out[b * 256 + c0 + cc] = s;
    }
}

// ---------------------------------------------------------------------------
// k_qkq (8 blocks = 1 head each, 512 thr): q-slice + kq + qkb fused.
//   P1: q[:, h*32..+32] = tv @ q_w[:, slice] + q_b  (32 cols x 16 K-slices)
//   P2: kq[b,h,c] = sum_d k_w[c,h*32+d]*q[b,h*32+d]  (k_w register-staged)
// ---------------------------------------------------------------------------
__global__ __launch_bounds__(512) void k_qkq(const float* __restrict__ tv,
                                             const float* __restrict__ q_w,
                                             const float* __restrict__ q_b,
                                             const float* __restrict__ k_w,
                                             const float* __restrict__ k_b,
                                             float* __restrict__ kq,
                                             float* __restrict__ qkb)
{
    __shared__ float xs[4096];          // tv [16][256]
    __shared__ float part[8192];        // [16 ks][16 b][32 cl]
    __shared__ float qs[512];           // q [16 b][32 d]
    int tid = threadIdx.x;
    int h   = blockIdx.x;

    for (int idx = tid; idx < 4096; idx += 512) xs[idx] = tv[idx];
    __syncthreads();

    {   // P1
        int cl = tid & 31, ks = tid >> 5;      // 32 cols x 16 K-slices (Kc=16)
        float acc[16];
        #pragma unroll
        for (int b = 0; b < 16; ++b) acc[b] = 0.f;
        const float* wp = q_w + (size_t)(ks * 16) * 256 + h * HD_ + cl;
        #pragma unroll
        for (int i = 0; i < 16; ++i) {
            float w = wp[(size_t)i * 256];
            int xi = ks * 16 + i;
            #pragma unroll
            for (int b = 0; b < 16; ++b) acc[b] += xs[b * 256 + xi] * w;
        }
        #pragma unroll
        for (int b = 0; b < 16; ++b) part[(ks * 16 + b) * 32 + cl] = acc[b];
    }
    __syncthreads();
    {   // reduce: tid covers (b, cl)
        int b = tid >> 5, cl = tid & 31;
        float s = 0.f;
        #pragma unroll
        for (int k2 = 0; k2 < 16; ++k2) s += part[(k2 * 16 + b) * 32 + cl];
        qs[b * 32 + cl] = s + q_b[h * HD_ + cl];
    }
    __syncthreads();
    if (tid < 16) {
        float s = 0.f;
        #pragma unroll
        for (int d = 0; d < 32; ++d) s += qs[tid * 32 + d] * k_b[h * HD_ + d];
        qkb[tid * NH_ + h] = s;
    }

    {   // P2: c = tid>>1, bh = tid&1 (8 batches each)
        int c = tid >> 1, bh = tid & 1;
        const float4* kwp = reinterpret_cast<const float4*>(k_w + (size_t)c * 256 + h * HD_);
        float4 kw[8];
        #pragma unroll
        for (int j = 0; j < 8; ++j) kw[j] = kwp[j];
        float acc[8] = {0,0,0,0,0,0,0,0};
        #pragma unroll
        for (int j = 0; j < 8; ++j) {
            float w0 = kw[j].x, w1 = kw[j].y, w2 = kw[j].z, w3 = kw[j].w;
            #pragma unroll
            for (int bi = 0; bi < 8; ++bi) {
                const float* qp = &qs[(bh * 8 + bi) * 32 + j * 4];
                acc[bi] += qp[0] * w0 + qp[1] * w1 + qp[2] * w2 + qp[3] * w3;
            }
        }
        #pragma unroll
        for (int bi = 0; bi < 8; ++bi)
            kq[((size_t)((bh * 8 + bi) * NH_ + h)) * C_ + c] = acc[bi];
    }
}

// ---------------------------------------------------------------------------
// K2: score partials, float4 along t, c split 8-way (32 c per block).
// sp[cq][b][h][t] = sum_{c in eighth} Fvis[b,c,t]*kq[b,h,c]
// grid (32, B): bx>>2 = cq (0..7), bx&3 = tc (0..3).
// ---------------------------------------------------------------------------
__global__ __launch_bounds__(256) void k2_scores(const float* __restrict__ F_vis,
                                                 const float* __restrict__ kq,
                                                 float* __restrict__ sp)
{
    int bx = blockIdx.x;
    int b  = blockIdx.y;
    int cq = bx >> 2;
    int tc = bx & 3;
    int tid = threadIdx.x;
    int t  = tc * 1024 + tid * 4;

    __shared__ float kqs[32][8];
    if (tid < 256) {
        for (int idx = tid; idx < 256; idx += 256) {
            int h = idx & 7, cl = idx >> 3;
            kqs[cl][h] = kq[((size_t)(b * NH_ + h)) * C_ + cq * 32 + cl];
        }
    }
    __syncthreads();

    const float* fv = F_vis + ((size_t)b * C_ + cq * 32) * T_ + t;

    float4 acc[8];
    #pragma unroll
    for (int h = 0; h < 8; ++h) acc[h] = make_float4(0.f, 0.f, 0.f, 0.f);

    #pragma unroll 8
    for (int cl = 0; cl < 32; ++cl) {
        float4 v = *reinterpret_cast<const float4*>(&fv[(size_t)cl * T_]);
        #pragma unroll
        for (int h = 0; h < 8; ++h) {
            float w = kqs[cl][h];
            acc[h].x += v.x * w; acc[h].y += v.y * w;
            acc[h].z += v.z * w; acc[h].w += v.w * w;
        }
    }
    #pragma unroll
    for (int h = 0; h < 8; ++h)
        *reinterpret_cast<float4*>(&sp[(((size_t)cq * B_ + b) * NH_ + h) * T_ + t]) = acc[h];
}

// ---------------------------------------------------------------------------
// K3: softmax over T per (b,h) from 8 partials; writes attn output
// ---------------------------------------------------------------------------
#define PSTRIDE ((size_t)B_ * NH_ * T_)
__global__ __launch_bounds__(256) void k3_softmax(const float* __restrict__ sp,
                                                  const float* __restrict__ qkb,
                                                  float* __restrict__ attn)
{
    int h = blockIdx.x, b = blockIdx.y, tid = threadIdx.x;
    const float scale = 0.176776695296636893f;  // 32^-0.5
    float bias = qkb[b * NH_ + h];
    const float* pp = sp + ((size_t)b * NH_ + h) * T_;

    float4 sv[4];
    float m = -1e30f;
    #pragma unroll
    for (int k = 0; k < 4; ++k) {
        int t = k * 1024 + tid * 4;
        float4 v = make_float4(bias, bias, bias, bias);
        #pragma unroll
        for (int p = 0; p < 8; ++p) {
            float4 a = *reinterpret_cast<const float4*>(&pp[p * PSTRIDE + t]);
            v.x += a.x; v.y += a.y; v.z += a.z; v.w += a.w;
        }
        v.x *= scale; v.y *= scale; v.z *= scale; v.w *= scale;
        sv[k] = v;
        m = fmaxf(m, fmaxf(fmaxf(v.x, v.y), fmaxf(v.z, v.w)));
    }
    __shared__ float red[8];
    #pragma unroll
    for (int o = 32; o; o >>= 1) m = fmaxf(m, __shfl_xor(m, o));
    int wid = tid >> 6, lane = tid & 63;
    if (lane == 0) red[wid] = m;
    __syncthreads();
    m = fmaxf(fmaxf(red[0], red[1]), fmaxf(red[2], red[3]));

    float sum = 0.f;
    #pragma unroll
    for (int k = 0; k < 4; ++k) {
        sv[k].x = expf(sv[k].x - m); sv[k].y = expf(sv[k].y - m);
        sv[k].z = expf(sv[k].z - m); sv[k].w = expf(sv[k].w - m);
        sum += sv[k].x + sv[k].y + sv[k].z + sv[k].w;
    }
    #pragma unroll
    for (int o = 32; o; o >>= 1) sum += __shfl_xor(sum, o);
    if (lane == 0) red[4 + wid] = sum;
    __syncthreads();
    sum = red[4] + red[5] + red[6] + red[7];
    float inv = 1.0f / sum;

    float* ap = attn + ((size_t)b * NH_ + h) * T_;
    #pragma unroll
    for (int k = 0; k < 4; ++k) {
        float4 v = sv[k];
        v.x *= inv; v.y *= inv; v.z *= inv; v.w *= inv;
        *reinterpret_cast<float4*>(&ap[k * 1024 + tid * 4]) = v;
    }
}

// ---------------------------------------------------------------------------
// K4: xa partials over half-t ranges (z = 0,1).  wave owns 4 channels.
// ---------------------------------------------------------------------------
__global__ __launch_bounds__(256, 2) void k4_xa(const float* __restrict__ F_vis,
                                                const float* __restrict__ attn,
                                                float* __restrict__ xa)
{
    int b = blockIdx.y, z = blockIdx.z;
    int tid = threadIdx.x, wid = tid >> 6, lane = tid & 63;
    int c0 = blockIdx.x * 16 + wid * 4;

    const float* ab = attn + (size_t)b * NH_ * T_;
    const float* fb = F_vis + (size_t)b * C_ * T_;

    float4 acc[4][8];
    #pragma unroll
    for (int j = 0; j < 4; ++j)
        #pragma unroll
        for (int h = 0; h < 8; ++h) acc[j][h] = make_float4(0.f, 0.f, 0.f, 0.f);

    for (int it = 0; it < 8; ++it) {
        int t = z * 2048 + it * 256 + lane * 4;
        float4 av[8];
        #pragma unroll
        for (int h = 0; h < 8; ++h)
            av[h] = *reinterpret_cast<const float4*>(&ab[(size_t)h * T_ + t]);
        #pragma unroll
        for (int j = 0; j < 4; ++j) {
            float4 f = *reinterpret_cast<const float4*>(&fb[(size_t)(c0 + j) * T_ + t]);
            #pragma unroll
            for (int h = 0; h < 8; ++h) {
                acc[j][h].x += f.x * av[h].x; acc[j][h].y += f.y * av[h].y;
                acc[j][h].z += f.z * av[h].z; acc[j][h].w += f.w * av[h].w;
            }
        }
    }
    #pragma unroll
    for (int j = 0; j < 4; ++j)
        #pragma unroll
        for (int h = 0; h < 8; ++h) {
            float v = acc[j][h].x + acc[j][h].y + acc[j][h].z + acc[j][h].w;
            #pragma unroll
            for (int o = 32; o; o >>= 1) v += __shfl_xor(v, o);
            if (lane == 0)
                xa[(((size_t)z * B_ + b) * NH_ + h) * C_ + c0 + j] = v;
        }
}

// ---------------------------------------------------------------------------
// K5: z = ((xa0+xa1) @ v_w + v_b) @ o_w + o_b;  gz = g * z
// ---------------------------------------------------------------------------
__global__ void k5_z(const float* __restrict__ xa,
                     const float* __restrict__ v_w, const float* __restrict__ v_b,
                     const float* __restrict__ o_w, const float* __restrict__ o_b,
                     const float* __restrict__ g,   float* __restrict__ gz)
{
    int b = blockIdx.x, j = threadIdx.x;
    __shared__ float zp[C_];
    int h = j >> 5;
    float s = v_b[j];
    const float* xr0 = xa + (((size_t)0 * B_ + b) * NH_ + h) * C_;
    const float* xr1 = xa + (((size_t)1 * B_ + b) * NH_ + h) * C_;
    #pragma unroll 8
    for (int c = 0; c < C_; c++) s += (xr0[c] + xr1[c]) * v_w[c * C_ + j];
    zp[j] = s;
    __syncthreads();
    float z = o_b[j];
    #pragma unroll 8
    for (int i = 0; i < C_; i++) z += zp[i] * o_w[i * C_ + j];
    gz[b * C_ + j] = g[b * C_ + j] * z;
}

// ---------------------------------------------------------------------------
// K6: fused residual+gate+LayerNorm, register-resident, shfl-reduce.
// ---------------------------------------------------------------------------
__global__ __launch_bounds__(256) void k6_ln(const float* __restrict__ F_vis,
                                             const float* __restrict__ gz,
                                             const float* __restrict__ ln_g,
                                             const float* __restrict__ ln_b,
                                             float* __restrict__ out)
{
    int b  = blockIdx.y;
    int t0 = blockIdx.x * 32;
    int tid = threadIdx.x;
    int t4 = tid & 7;
    int cb = tid >> 3;

    __shared__ float gzs[256], lgs[256], lbs[256];
    __shared__ float4 redS[4][8], redQ[4][8];
    __shared__ float4 mu4s[8], rs4s[8];

    gzs[tid] = gz[b * C_ + tid];
    lgs[tid] = ln_g[tid];
    lbs[tid] = ln_b[tid];
    __syncthreads();

    const float* fvb = F_vis + (size_t)b * C_ * T_ + t0 + t4 * 4;
    float4 v[8];
    float4 s = make_float4(0.f, 0.f, 0.f, 0.f);
    float4 q = make_float4(0.f, 0.f, 0.f, 0.f);
    #pragma unroll
    for (int k = 0; k < 8; ++k) {
        int c = cb + k * 32;
        float4 x = *reinterpret_cast<const float4*>(&fvb[(size_t)c * T_]);
        float gc = gzs[c];
        x.x += gc; x.y += gc; x.z += gc; x.w += gc;
        v[k] = x;
        s.x += x.x; s.y += x.y; s.z += x.z; s.w += x.w;
        q.x += x.x * x.x; q.y += x.y * x.y; q.z += x.z * x.z; q.w += x.w * x.w;
    }
    #pragma unroll
    for (int o = 8; o <= 32; o <<= 1) {
        s.x += __shfl_xor(s.x, o); s.y += __shfl_xor(s.y, o);
        s.z += __shfl_xor(s.z, o); s.w += __shfl_xor(s.w, o);
        q.x += __shfl_xor(q.x, o); q.y += __shfl_xor(q.y, o);
        q.z += __shfl_xor(q.z, o); q.w += __shfl_xor(q.w, o);
    }
    int wid = tid >> 6;
    if ((tid & 63) < 8) { redS[wid][t4] = s; redQ[wid][t4] = q; }
    __syncthreads();
    if (tid < 8) {
        float4 S = redS[0][tid], Q = redQ[0][tid];
        #pragma unroll
        for (int w = 1; w < 4; ++w) {
            float4 a = redS[w][tid], c2 = redQ[w][tid];
            S.x += a.x; S.y += a.y; S.z += a.z; S.w += a.w;
            Q.x += c2.x; Q.y += c2.y; Q.z += c2.z; Q.w += c2.w;
        }
        float4 mu, rs;
        mu.x = S.x * (1.0f / C_); mu.y = S.y * (1.0f / C_);
        mu.z = S.z * (1.0f / C_); mu.w = S.w * (1.0f / C_);
        rs.x = rsqrtf(fmaxf(Q.x * (1.0f / C_) - mu.x * mu.x, 0.f) + 1e-5f);
        rs.y = rsqrtf(fmaxf(Q.y * (1.0f / C_) - mu.y * mu.y, 0.f) + 1e-5f);
        rs.z = rsqrtf(fmaxf(Q.z * (1.0f / C_) - mu.z * mu.z, 0.f) + 1e-5f);
        rs.w = rsqrtf(fmaxf(Q.w * (1.0f / C_) - mu.w * mu.w, 0.f) + 1e-5f);
        mu4s[tid] = mu; rs4s[tid] = rs;
    }
    __syncthreads();
    float4 mu = mu4s[t4], rs = rs4s[t4];
    float* ob = out + (size_t)b * C_ * T_ + t0 + t4 * 4;
    #pragma unroll
    for (int k = 0; k < 8; ++k) {
        int c = cb + k * 32;
        float lg = lgs[c], lb = lbs[c];
        float4 o;
        o.x = (v[k].x - mu.x) * rs.x * lg + lb;
        o.y = (v[k].y - mu.y) * rs.y * lg + lb;
        o.z = (v[k].z - mu.z) * rs.z * lg + lb;
        o.w = (v[k].w - mu.w) * rs.w * lg + lb;
        *reinterpret_cast<float4*>(&ob[(size_t)c * T_]) = o;
    }
}

// ---------------------------------------------------------------------------
extern "C" void kernel_launch(void* const* d_in, const int* in_sizes, int n_in,
                              void* d_out, int out_size, void* d_ws, size_t ws_size,
                              hipStream_t stream)
{
    const float* F_vis     = (const float*)d_in[0];
    const float* F_text    = (const float*)d_in[1];
    const float* F_unified = (const float*)d_in[2];
    const float* F_teacher = (const float*)d_in[3];
    const float* tp_w1 = (const float*)d_in[4];
    const float* tp_b1 = (const float*)d_in[5];
    const float* tp_w2 = (const float*)d_in[6];
    const float* tp_b2 = (const float*)d_in[7];
    const float* q_w   = (const float*)d_in[8];
    const float* q_b   = (const float*)d_in[9];
    const float* k_w   = (const float*)d_in[10];
    const float* k_b   = (const float*)d_in[11];
    const float* v_w   = (const float*)d_in[12];
    const float* v_b   = (const float*)d_in[13];
    const float* o_w   = (const float*)d_in[14];
    const float* o_b   = (const float*)d_in[15];
    const float* fa_w  = (const float*)d_in[16];
    const float* fa_b  = (const float*)d_in[17];
    const float* gp_w  = (const float*)d_in[18];
    const float* gp_b  = (const float*)d_in[19];
    const float* ln_g  = (const float*)d_in[20];
    const float* ln_b  = (const float*)d_in[21];

    float* ws  = (float*)d_ws;
    float* t1  = ws;                    // 4096
    float* tv  = ws + 4096;             // 4096
    float* kq  = ws + 8192;             // 32768
    float* qkb = ws + 40960;            // 128
    float* g   = ws + 41088;            // 4096
    float* gz  = ws + 45184;            // 4096
    float* xa  = ws + 49280;            // 2 x 32768 = 65536

    float* out  = (float*)d_out;
    float* attn = out + (size_t)B_ * C_ * T_;    // output #1 region
    float* sp   = out;                           // scratch in y-region (16 MiB)

    k_t1gate<<<16, 512, 0, stream>>>(F_text, F_unified, F_teacher,
                                     tp_w1, tp_b1, fa_w, fa_b, gp_w, gp_b,
                                     t1, g);
    gemm16<256, 0><<<16, 512, 0, stream>>>(t1, tp_w2, tp_b2, tv);
    k_qkq<<<NH_, 512, 0, stream>>>(tv, q_w, q_b, k_w, k_b, kq, qkb);

    k2_scores<<<dim3(32, B_), 256, 0, stream>>>(F_vis, kq, sp);
    k3_softmax<<<dim3(NH_, B_), 256, 0, stream>>>(sp, qkb, attn);
    k4_xa<<<dim3(16, B_, 2), 256, 0, stream>>>(F_vis, attn, xa);
    k5_z<<<B_, 256, 0, stream>>>(xa, v_w, v_b, o_w, o_b, g, gz);
    k6_ln<<<dim3(128, B_), 256, 0, stream>>>(F_vis, gz, ln_g, ln_b, out);
}